// Round 6
// baseline (859.482 us; speedup 1.0000x reference)
//
#include <hip/hip_runtime.h>
#include <cstddef>
#include <math.h>

typedef float v4 __attribute__((ext_vector_type(4)));

#define IMG_H 800
#define IMG_W 1216
#define FH 25
#define FWW 38
#define NBOX 2000
#define NKEEP 8
#define D1 100352   /* 2048*49 */
#define K1 4096
#define NSLICE 16
#define DPS (D1/NSLICE)  /* 6272 */

// ---------------------------------------------------------------------------
// Kernel 1: greedy NMS (exact replica of reference loop) + ROI quantization.
// 1024 threads: 2-stride scans, 10-level tree reduce.
// ---------------------------------------------------------------------------
__global__ __launch_bounds__(1024) void nms_sel_kernel(const float* __restrict__ rois,
                                                       const float* __restrict__ scores,
                                                       int* __restrict__ roi_out) {
    __shared__ float4 s_box[NBOX];
    __shared__ float  s_fg[NBOX];
    __shared__ float  red_v[1024];
    __shared__ int    red_i[1024];
    __shared__ int    s_sels[NKEEP];
    const int tid = threadIdx.x;

    for (int i = tid; i < NBOX; i += 1024) {
        float x1 = rois[i*4+0], y1 = rois[i*4+1], x2 = rois[i*4+2], y2 = rois[i*4+3];
        s_box[i] = make_float4(x1, y1, x2, y2);
        bool valid = (x1 >= 0.f) && (y1 >= 0.f) && (x2 <= (float)IMG_W) && (y2 <= (float)IMG_H);
        s_fg[i] = valid ? scores[i*2+1] : -INFINITY;
    }
    __syncthreads();

    for (int it = 0; it < NKEEP; ++it) {
        float bv = -INFINITY; int bi = NBOX;
        for (int i = tid; i < NBOX; i += 1024) {
            float v = s_fg[i];
            if (v > bv || (v == bv && i < bi)) { bv = v; bi = i; }
        }
        red_v[tid] = bv; red_i[tid] = bi;
        __syncthreads();
        for (int off = 512; off > 0; off >>= 1) {
            if (tid < off) {
                float v = red_v[tid+off]; int ii = red_i[tid+off];
                if (v > red_v[tid] || (v == red_v[tid] && ii < red_i[tid])) {
                    red_v[tid] = v; red_i[tid] = ii;
                }
            }
            __syncthreads();
        }
        int s = red_i[0];
        if (s >= NBOX) s = 0;
        if (tid == 0) s_sels[it] = s;

        float4 bs = s_box[s];
        float a1 = (bs.z - bs.x) * (bs.w - bs.y);
        for (int i = tid; i < NBOX; i += 1024) {
            float4 b = s_box[i];
            float ix1 = fmaxf(bs.x, b.x), iy1 = fmaxf(bs.y, b.y);
            float ix2 = fminf(bs.z, b.z), iy2 = fminf(bs.w, b.w);
            float inter = fmaxf(ix2 - ix1, 0.f) * fmaxf(iy2 - iy1, 0.f);
            float a2 = (b.z - b.x) * (b.w - b.y);
            float iou = inter / (a1 + a2 - inter);
            if (!(iou <= 0.6f)) s_fg[i] = -INFINITY;
        }
        __syncthreads();
    }

    if (tid < NKEEP) {
        int s = s_sels[tid];
        float4 b = s_box[s];
        int x = (int)floorf(b.x / 32.0f + 0.5f);
        int y = (int)floorf(b.y / 32.0f + 0.5f);
        int w = (int)floorf(b.z / 32.0f + 1.0f);
        int h = (int)floorf(b.w / 32.0f + 1.0f);
        bool bad = (x < 0) || (x >= FWW) || (y < 0) || (y >= FH) ||
                   (w < 1) || (x + w > FWW) || (h < 1) || (y + h > FH);
        if (bad) { x = 0; y = 0; w = FWW; h = FH; }
        roi_out[tid*4+0] = x; roi_out[tid*4+1] = y;
        roi_out[tid*4+2] = w; roi_out[tid*4+3] = h;
    }
}

// ---------------------------------------------------------------------------
// Kernel 2: adaptive 7x7 max-pool. pooled flat: idx = r*D1 + c*49 + i*7 + j
// ---------------------------------------------------------------------------
__global__ __launch_bounds__(256) void roi_pool_kernel(const float* __restrict__ feat,
                                                       const int* __restrict__ roi_out,
                                                       float* __restrict__ pooled) {
    int idx = blockIdx.x * 256 + threadIdx.x;
    if (idx >= NKEEP * D1) return;
    int r    = idx / D1;
    int rem  = idx - r * D1;
    int c    = rem / 49;
    int cell = rem - c * 49;
    int i = cell / 7;
    int j = cell - i * 7;
    int x = roi_out[r*4+0], y = roi_out[r*4+1], w = roi_out[r*4+2], h = roi_out[r*4+3];
    int r0 = y + (i * h) / 7;
    int r1 = y + ((i + 1) * h + 6) / 7;
    int c0 = x + (j * w) / 7;
    int c1 = x + ((j + 1) * w + 6) / 7;
    const float* fc = feat + (size_t)c * (FH * FWW);
    float m = -INFINITY;
    for (int rr = r0; rr < r1; ++rr) {
        const float* fr = fc + rr * FWW;
        for (int cc2 = c0; cc2 < c1; ++cc2) m = fmaxf(m, fr[cc2]);
    }
    pooled[idx] = m;
}

// ---------------------------------------------------------------------------
// Kernel 3: o[n][k] = b[k]  (bias init; fc1 atomically accumulates on top)
// ---------------------------------------------------------------------------
__global__ __launch_bounds__(256) void init_bias8_kernel(const float* __restrict__ b,
                                                         float* __restrict__ o, int K) {
    int i = blockIdx.x * 256 + threadIdx.x;
    if (i < NKEEP * K) o[i] = b[i & (K - 1)];
}

// ---------------------------------------------------------------------------
// Kernel 4: FC1, TLP-lean: 2 rows/thread, ROIs split in two 4-groups to
// keep VGPR <= 64 -> 8 waves/SIMD (32 waves/CU). Grid = 2048 blocks
// (128 kb x 16 ds) = one full generation at 8 blocks/CU.
// ---------------------------------------------------------------------------
__global__ __launch_bounds__(256, 8) void fc1_kernel(const float* __restrict__ w1,
                                                     const float* __restrict__ flat,
                                                     float* __restrict__ o1) {
    const int kb = blockIdx.x >> 4;       // 0..127
    const int ds = blockIdx.x & 15;       // 0..15
    const int tid = threadIdx.x;
    const int kq = tid >> 4;              // 0..15
    const int dl = tid & 15;              // 0..15
    const int k0 = kb * 32 + kq * 2;      // 2 rows per thread
    const int dbase = ds * DPS + dl * 4;

    const float* wp = w1 + (size_t)k0 * D1 + dbase;
    const float* fp = flat + dbase;

    float acc[2][8];
    #pragma unroll
    for (int a = 0; a < 2; ++a)
        #pragma unroll
        for (int n = 0; n < 8; ++n) acc[a][n] = 0.f;

    for (int itn = 0; itn < DPS / 64; ++itn) {   // 98 iters of 64 cols
        const int off = itn * 64;
        v4 wv0 = *(const v4*)(wp + off);
        v4 wv1 = *(const v4*)(wp + (size_t)D1 + off);
        {   // ROIs 0..3
            v4 fv[4];
            #pragma unroll
            for (int n = 0; n < 4; ++n) fv[n] = *(const v4*)(fp + (size_t)n * D1 + off);
            #pragma unroll
            for (int n = 0; n < 4; ++n) {
                acc[0][n] += wv0[0]*fv[n][0] + wv0[1]*fv[n][1] + wv0[2]*fv[n][2] + wv0[3]*fv[n][3];
                acc[1][n] += wv1[0]*fv[n][0] + wv1[1]*fv[n][1] + wv1[2]*fv[n][2] + wv1[3]*fv[n][3];
            }
        }
        {   // ROIs 4..7
            v4 fv[4];
            #pragma unroll
            for (int n = 0; n < 4; ++n) fv[n] = *(const v4*)(fp + (size_t)(n + 4) * D1 + off);
            #pragma unroll
            for (int n = 0; n < 4; ++n) {
                acc[0][n+4] += wv0[0]*fv[n][0] + wv0[1]*fv[n][1] + wv0[2]*fv[n][2] + wv0[3]*fv[n][3];
                acc[1][n+4] += wv1[0]*fv[n][0] + wv1[1]*fv[n][1] + wv1[2]*fv[n][2] + wv1[3]*fv[n][3];
            }
        }
    }

    // reduce across the 16 d-lanes, then atomic into o1
    #pragma unroll
    for (int a = 0; a < 2; ++a) {
        #pragma unroll
        for (int n = 0; n < 8; ++n) {
            float v = acc[a][n];
            v += __shfl_xor(v, 1);
            v += __shfl_xor(v, 2);
            v += __shfl_xor(v, 4);
            v += __shfl_xor(v, 8);
            if (dl == 0) atomicAdd(&o1[n * K1 + k0 + a], v);
        }
    }
}

// ---------------------------------------------------------------------------
// Kernel 5: FC2 — 2 waves per output row (split-K halves), LDS pair-reduce.
// 2048 blocks x 4 waves = 8192 waves; lean VGPR -> 8 waves/SIMD.
// ---------------------------------------------------------------------------
__global__ __launch_bounds__(256, 8) void fc2_kernel(const float* __restrict__ w2,
                                                     const float* __restrict__ o1,
                                                     const float* __restrict__ b2,
                                                     float* __restrict__ o2) {
    __shared__ float red[4][8];
    const int tid  = threadIdx.x;
    const int wid  = tid >> 6;            // 0..3
    const int lane = tid & 63;
    const int row  = blockIdx.x * 2 + (wid >> 1);   // 2 rows per block
    const int half = wid & 1;
    const int base = half * (K1 / 2);     // 2048-col half

    const float* wr = w2 + (size_t)row * K1 + base + lane * 4;
    const float* fo = o1 + base + lane * 4;

    float acc[8];
    #pragma unroll
    for (int n = 0; n < 8; ++n) acc[n] = 0.f;
    #pragma unroll
    for (int i = 0; i < 8; ++i) {          // 8 iters x 256 cols
        const int off = i * 256;
        v4 wv = *(const v4*)(wr + off);
        #pragma unroll
        for (int n = 0; n < 8; ++n) {
            v4 f = *(const v4*)(fo + (size_t)n * K1 + off);
            acc[n] += wv[0]*f[0] + wv[1]*f[1] + wv[2]*f[2] + wv[3]*f[3];
        }
    }
    #pragma unroll
    for (int n = 0; n < 8; ++n) {
        float v = acc[n];
        v += __shfl_xor(v, 1);  v += __shfl_xor(v, 2);
        v += __shfl_xor(v, 4);  v += __shfl_xor(v, 8);
        v += __shfl_xor(v, 16); v += __shfl_xor(v, 32);
        if (lane == 0) red[wid][n] = v;
    }
    __syncthreads();
    if (tid < 16) {
        int p = tid >> 3;                  // which row of this block
        int n = tid & 7;
        int r = blockIdx.x * 2 + p;
        float v = red[p*2][n] + red[p*2+1][n];
        o2[n * K1 + r] = v + b2[r];
    }
}

// ---------------------------------------------------------------------------
// Kernel 6: heads. k<81 -> wc/bc, else wl/bl. out (8,405) row-major.
// ---------------------------------------------------------------------------
__global__ __launch_bounds__(256) void fc3_kernel(const float* __restrict__ wc,
                                                  const float* __restrict__ bc,
                                                  const float* __restrict__ wl,
                                                  const float* __restrict__ bl,
                                                  const float* __restrict__ o2,
                                                  float* __restrict__ out) {
    int gw   = (blockIdx.x * 256 + threadIdx.x) >> 6;
    int lane = threadIdx.x & 63;
    if (gw >= 405) return;
    const float* wrow; float bias;
    if (gw < 81) { wrow = wc + (size_t)gw * K1;        bias = bc[gw]; }
    else         { wrow = wl + (size_t)(gw - 81) * K1; bias = bl[gw - 81]; }
    const float4* wr = (const float4*)wrow;
    const float4* fo = (const float4*)o2;
    float acc[8];
    #pragma unroll
    for (int n = 0; n < 8; ++n) acc[n] = 0.f;
    for (int itn = 0; itn < K1 / 256; ++itn) {
        float4 wv = wr[itn * 64 + lane];
        #pragma unroll
        for (int n = 0; n < 8; ++n) {
            float4 f = fo[n * (K1/4) + itn * 64 + lane];
            acc[n] += wv.x*f.x + wv.y*f.y + wv.z*f.z + wv.w*f.w;
        }
    }
    #pragma unroll
    for (int n = 0; n < 8; ++n) {
        float v = acc[n];
        #pragma unroll
        for (int m = 32; m >= 1; m >>= 1) v += __shfl_xor(v, m);
        if (lane == 0) out[n * 405 + gw] = v + bias;
    }
}

// ---------------------------------------------------------------------------
extern "C" void kernel_launch(void* const* d_in, const int* in_sizes, int n_in,
                              void* d_out, int out_size, void* d_ws, size_t ws_size,
                              hipStream_t stream) {
    const float* feat   = (const float*)d_in[0];
    const float* rois   = (const float*)d_in[1];
    const float* scores = (const float*)d_in[2];
    const float* w1     = (const float*)d_in[3];
    const float* b1     = (const float*)d_in[4];
    const float* w2     = (const float*)d_in[5];
    const float* b2     = (const float*)d_in[6];
    const float* wc     = (const float*)d_in[7];
    const float* bc     = (const float*)d_in[8];
    const float* wl     = (const float*)d_in[9];
    const float* bl     = (const float*)d_in[10];
    float* out = (float*)d_out;

    // workspace layout (floats): [0..255] roi ints, then pooled, o1, o2
    int*   roi_out = (int*)d_ws;
    float* pooled  = (float*)d_ws + 256;
    float* o1      = pooled + (size_t)NKEEP * D1;
    float* o2      = o1 + NKEEP * K1;

    nms_sel_kernel<<<1, 1024, 0, stream>>>(rois, scores, roi_out);
    roi_pool_kernel<<<(NKEEP * D1 + 255) / 256, 256, 0, stream>>>(feat, roi_out, pooled);
    init_bias8_kernel<<<(NKEEP * K1 + 255) / 256, 256, 0, stream>>>(b1, o1, K1);
    fc1_kernel<<<128 * NSLICE, 256, 0, stream>>>(w1, pooled, o1);
    fc2_kernel<<<K1 / 2, 256, 0, stream>>>(w2, o1, b2, o2);
    fc3_kernel<<<(405 * 64 + 255) / 256, 256, 0, stream>>>(wc, bc, wl, bl, o2, out);
}

// Round 7
// 843.920 us; speedup vs baseline: 1.0184x; 1.0184x over previous
//
#include <hip/hip_runtime.h>
#include <cstddef>
#include <math.h>

typedef float v4 __attribute__((ext_vector_type(4)));

#define IMG_H 800
#define IMG_W 1216
#define FH 25
#define FWW 38
#define NBOX 2000
#define NKEEP 8
#define D1 100352   /* 2048*49 */
#define K1 4096

// ---------------------------------------------------------------------------
// Kernel 1: greedy NMS (exact replica of reference loop) + ROI quantization.
// ---------------------------------------------------------------------------
__global__ __launch_bounds__(256) void nms_sel_kernel(const float* __restrict__ rois,
                                                      const float* __restrict__ scores,
                                                      int* __restrict__ roi_out) {
    __shared__ float4 s_box[NBOX];
    __shared__ float  s_fg[NBOX];
    __shared__ float  red_v[256];
    __shared__ int    red_i[256];
    __shared__ int    s_sels[NKEEP];
    const int tid = threadIdx.x;

    for (int i = tid; i < NBOX; i += 256) {
        float x1 = rois[i*4+0], y1 = rois[i*4+1], x2 = rois[i*4+2], y2 = rois[i*4+3];
        s_box[i] = make_float4(x1, y1, x2, y2);
        bool valid = (x1 >= 0.f) && (y1 >= 0.f) && (x2 <= (float)IMG_W) && (y2 <= (float)IMG_H);
        s_fg[i] = valid ? scores[i*2+1] : -INFINITY;
    }
    __syncthreads();

    for (int it = 0; it < NKEEP; ++it) {
        float bv = -INFINITY; int bi = NBOX;
        for (int i = tid; i < NBOX; i += 256) {
            float v = s_fg[i];
            if (v > bv || (v == bv && i < bi)) { bv = v; bi = i; }
        }
        red_v[tid] = bv; red_i[tid] = bi;
        __syncthreads();
        for (int off = 128; off > 0; off >>= 1) {
            if (tid < off) {
                float v = red_v[tid+off]; int ii = red_i[tid+off];
                if (v > red_v[tid] || (v == red_v[tid] && ii < red_i[tid])) {
                    red_v[tid] = v; red_i[tid] = ii;
                }
            }
            __syncthreads();
        }
        int s = red_i[0];
        if (s >= NBOX) s = 0;
        if (tid == 0) s_sels[it] = s;

        float4 bs = s_box[s];
        float a1 = (bs.z - bs.x) * (bs.w - bs.y);
        for (int i = tid; i < NBOX; i += 256) {
            float4 b = s_box[i];
            float ix1 = fmaxf(bs.x, b.x), iy1 = fmaxf(bs.y, b.y);
            float ix2 = fminf(bs.z, b.z), iy2 = fminf(bs.w, b.w);
            float inter = fmaxf(ix2 - ix1, 0.f) * fmaxf(iy2 - iy1, 0.f);
            float a2 = (b.z - b.x) * (b.w - b.y);
            float iou = inter / (a1 + a2 - inter);
            if (!(iou <= 0.6f)) s_fg[i] = -INFINITY;
        }
        __syncthreads();
    }

    if (tid < NKEEP) {
        int s = s_sels[tid];
        float4 b = s_box[s];
        int x = (int)floorf(b.x / 32.0f + 0.5f);
        int y = (int)floorf(b.y / 32.0f + 0.5f);
        int w = (int)floorf(b.z / 32.0f + 1.0f);
        int h = (int)floorf(b.w / 32.0f + 1.0f);
        bool bad = (x < 0) || (x >= FWW) || (y < 0) || (y >= FH) ||
                   (w < 1) || (x + w > FWW) || (h < 1) || (y + h > FH);
        if (bad) { x = 0; y = 0; w = FWW; h = FH; }
        roi_out[tid*4+0] = x; roi_out[tid*4+1] = y;
        roi_out[tid*4+2] = w; roi_out[tid*4+3] = h;
    }
}

// ---------------------------------------------------------------------------
// Kernel 2: adaptive 7x7 max-pool. pooled flat: idx = r*D1 + c*49 + i*7 + j
// ---------------------------------------------------------------------------
__global__ __launch_bounds__(256) void roi_pool_kernel(const float* __restrict__ feat,
                                                       const int* __restrict__ roi_out,
                                                       float* __restrict__ pooled) {
    int idx = blockIdx.x * 256 + threadIdx.x;
    if (idx >= NKEEP * D1) return;
    int r    = idx / D1;
    int rem  = idx - r * D1;
    int c    = rem / 49;
    int cell = rem - c * 49;
    int i = cell / 7;
    int j = cell - i * 7;
    int x = roi_out[r*4+0], y = roi_out[r*4+1], w = roi_out[r*4+2], h = roi_out[r*4+3];
    int r0 = y + (i * h) / 7;
    int r1 = y + ((i + 1) * h + 6) / 7;
    int c0 = x + (j * w) / 7;
    int c1 = x + ((j + 1) * w + 6) / 7;
    const float* fc = feat + (size_t)c * (FH * FWW);
    float m = -INFINITY;
    for (int rr = r0; rr < r1; ++rr) {
        const float* fr = fc + rr * FWW;
        for (int cc2 = c0; cc2 < c1; ++cc2) m = fmaxf(m, fr[cc2]);
    }
    pooled[idx] = m;
}

// ---------------------------------------------------------------------------
// Kernel 3: FC1 v7 — one wave per w1 row; wave reads contiguous 1KB/instr
// (fill-pattern streaming, 4096 monotone device streams). 256 blocks x
// 1024 threads = 16 rows/block; f-traffic 819MB L2 (L1-filtered), fully
// overlapped. 2-deep w register prefetch. Wave shfl-reduce writes o1+b1
// directly — no atomics, no init kernel. ~75 VGPR, no spills.
// ---------------------------------------------------------------------------
__global__ __launch_bounds__(1024) void fc1_kernel(const float* __restrict__ w1,
                                                   const float* __restrict__ flat,
                                                   const float* __restrict__ b1,
                                                   float* __restrict__ o1) {
    const int row  = blockIdx.x * 16 + (threadIdx.x >> 6);
    const int lane = threadIdx.x & 63;

    const float* wp = w1 + (size_t)row * D1 + lane * 4;
    const float* fp = flat + lane * 4;

    float acc[8];
    #pragma unroll
    for (int n = 0; n < 8; ++n) acc[n] = 0.f;

    // 2-deep prefetch: wcur = tile 0, wnxt = tile 1
    v4 wcur = *(const v4*)(wp);
    v4 wnxt = *(const v4*)(wp + 256);

    for (int it = 0; it < D1 / 256; ++it) {      // 392 tiles of 256 cols
        const int off = it * 256;
        // f loads for this tile (L1/L2-resident, shared across the 16 waves)
        v4 fv[8];
        #pragma unroll
        for (int n = 0; n < 8; ++n) fv[n] = *(const v4*)(fp + (size_t)n * D1 + off);

        // prefetch w tile it+2 (dummy re-read of tile 0 on the last two)
        const int offp = (it < D1 / 256 - 2) ? off + 512 : 0;
        v4 wpre = *(const v4*)(wp + offp);

        // FMA on the tile loaded two iterations ago
        #pragma unroll
        for (int n = 0; n < 8; ++n) {
            acc[n] += wcur[0]*fv[n][0] + wcur[1]*fv[n][1]
                    + wcur[2]*fv[n][2] + wcur[3]*fv[n][3];
        }
        wcur = wnxt;
        wnxt = wpre;
    }

    // reduce each ROI's partial across the wave's 64 lanes
    #pragma unroll
    for (int n = 0; n < 8; ++n) {
        float v = acc[n];
        v += __shfl_xor(v, 1);
        v += __shfl_xor(v, 2);
        v += __shfl_xor(v, 4);
        v += __shfl_xor(v, 8);
        v += __shfl_xor(v, 16);
        v += __shfl_xor(v, 32);
        if (lane == 0) o1[n * K1 + row] = v + b1[row];
    }
}

// ---------------------------------------------------------------------------
// Kernel 4: FC2 (8x4096)@(4096x4096). One wave per output row k.
// ---------------------------------------------------------------------------
__global__ __launch_bounds__(256) void fc2_kernel(const float* __restrict__ w2,
                                                  const float* __restrict__ o1,
                                                  const float* __restrict__ b2,
                                                  float* __restrict__ o2) {
    int gw   = (blockIdx.x * 256 + threadIdx.x) >> 6;
    int lane = threadIdx.x & 63;
    if (gw >= K1) return;
    const float4* wr = (const float4*)(w2 + (size_t)gw * K1);
    const float4* fo = (const float4*)o1;
    float acc[8];
    #pragma unroll
    for (int n = 0; n < 8; ++n) acc[n] = 0.f;
    for (int itn = 0; itn < K1 / 256; ++itn) {   // 16
        float4 wv = wr[itn * 64 + lane];
        #pragma unroll
        for (int n = 0; n < 8; ++n) {
            float4 f = fo[n * (K1/4) + itn * 64 + lane];
            acc[n] += wv.x*f.x + wv.y*f.y + wv.z*f.z + wv.w*f.w;
        }
    }
    #pragma unroll
    for (int n = 0; n < 8; ++n) {
        float v = acc[n];
        #pragma unroll
        for (int m = 32; m >= 1; m >>= 1) v += __shfl_xor(v, m);
        if (lane == 0) o2[n * K1 + gw] = v + b2[gw];
    }
}

// ---------------------------------------------------------------------------
// Kernel 5: heads. k<81 -> wc/bc, else wl/bl. out (8,405) row-major.
// ---------------------------------------------------------------------------
__global__ __launch_bounds__(256) void fc3_kernel(const float* __restrict__ wc,
                                                  const float* __restrict__ bc,
                                                  const float* __restrict__ wl,
                                                  const float* __restrict__ bl,
                                                  const float* __restrict__ o2,
                                                  float* __restrict__ out) {
    int gw   = (blockIdx.x * 256 + threadIdx.x) >> 6;
    int lane = threadIdx.x & 63;
    if (gw >= 405) return;
    const float* wrow; float bias;
    if (gw < 81) { wrow = wc + (size_t)gw * K1;        bias = bc[gw]; }
    else         { wrow = wl + (size_t)(gw - 81) * K1; bias = bl[gw - 81]; }
    const float4* wr = (const float4*)wrow;
    const float4* fo = (const float4*)o2;
    float acc[8];
    #pragma unroll
    for (int n = 0; n < 8; ++n) acc[n] = 0.f;
    for (int itn = 0; itn < K1 / 256; ++itn) {
        float4 wv = wr[itn * 64 + lane];
        #pragma unroll
        for (int n = 0; n < 8; ++n) {
            float4 f = fo[n * (K1/4) + itn * 64 + lane];
            acc[n] += wv.x*f.x + wv.y*f.y + wv.z*f.z + wv.w*f.w;
        }
    }
    #pragma unroll
    for (int n = 0; n < 8; ++n) {
        float v = acc[n];
        #pragma unroll
        for (int m = 32; m >= 1; m >>= 1) v += __shfl_xor(v, m);
        if (lane == 0) out[n * 405 + gw] = v + bias;
    }
}

// ---------------------------------------------------------------------------
extern "C" void kernel_launch(void* const* d_in, const int* in_sizes, int n_in,
                              void* d_out, int out_size, void* d_ws, size_t ws_size,
                              hipStream_t stream) {
    const float* feat   = (const float*)d_in[0];
    const float* rois   = (const float*)d_in[1];
    const float* scores = (const float*)d_in[2];
    const float* w1     = (const float*)d_in[3];
    const float* b1     = (const float*)d_in[4];
    const float* w2     = (const float*)d_in[5];
    const float* b2     = (const float*)d_in[6];
    const float* wc     = (const float*)d_in[7];
    const float* bc     = (const float*)d_in[8];
    const float* wl     = (const float*)d_in[9];
    const float* bl     = (const float*)d_in[10];
    float* out = (float*)d_out;

    // workspace layout (floats): [0..255] roi ints, then pooled, o1, o2
    int*   roi_out = (int*)d_ws;
    float* pooled  = (float*)d_ws + 256;
    float* o1      = pooled + (size_t)NKEEP * D1;
    float* o2      = o1 + NKEEP * K1;

    nms_sel_kernel<<<1, 256, 0, stream>>>(rois, scores, roi_out);
    roi_pool_kernel<<<(NKEEP * D1 + 255) / 256, 256, 0, stream>>>(feat, roi_out, pooled);
    fc1_kernel<<<256, 1024, 0, stream>>>(w1, pooled, b1, o1);
    fc2_kernel<<<K1 / 4, 256, 0, stream>>>(w2, o1, b2, o2);
    fc3_kernel<<<(405 * 64 + 255) / 256, 256, 0, stream>>>(wc, bc, wl, bl, o2, out);
}

// Round 8
// 593.376 us; speedup vs baseline: 1.4485x; 1.4222x over previous
//
#include <hip/hip_runtime.h>
#include <cstddef>
#include <math.h>

typedef float v4 __attribute__((ext_vector_type(4)));

#define IMG_H 800
#define IMG_W 1216
#define FH 25
#define FWW 38
#define NBOX 2000
#define NKEEP 8
#define D1 100352   /* 2048*49 */
#define K1 4096
#define NSLICE 16
#define DPS (D1/NSLICE)  /* 6272 */

// ---------------------------------------------------------------------------
// Kernel 1: greedy NMS (exact replica of reference loop) + ROI quantization.
// ---------------------------------------------------------------------------
__global__ __launch_bounds__(256) void nms_sel_kernel(const float* __restrict__ rois,
                                                      const float* __restrict__ scores,
                                                      int* __restrict__ roi_out) {
    __shared__ float4 s_box[NBOX];
    __shared__ float  s_fg[NBOX];
    __shared__ float  red_v[256];
    __shared__ int    red_i[256];
    __shared__ int    s_sels[NKEEP];
    const int tid = threadIdx.x;

    for (int i = tid; i < NBOX; i += 256) {
        float x1 = rois[i*4+0], y1 = rois[i*4+1], x2 = rois[i*4+2], y2 = rois[i*4+3];
        s_box[i] = make_float4(x1, y1, x2, y2);
        bool valid = (x1 >= 0.f) && (y1 >= 0.f) && (x2 <= (float)IMG_W) && (y2 <= (float)IMG_H);
        s_fg[i] = valid ? scores[i*2+1] : -INFINITY;
    }
    __syncthreads();

    for (int it = 0; it < NKEEP; ++it) {
        float bv = -INFINITY; int bi = NBOX;
        for (int i = tid; i < NBOX; i += 256) {
            float v = s_fg[i];
            if (v > bv || (v == bv && i < bi)) { bv = v; bi = i; }
        }
        red_v[tid] = bv; red_i[tid] = bi;
        __syncthreads();
        for (int off = 128; off > 0; off >>= 1) {
            if (tid < off) {
                float v = red_v[tid+off]; int ii = red_i[tid+off];
                if (v > red_v[tid] || (v == red_v[tid] && ii < red_i[tid])) {
                    red_v[tid] = v; red_i[tid] = ii;
                }
            }
            __syncthreads();
        }
        int s = red_i[0];
        if (s >= NBOX) s = 0;
        if (tid == 0) s_sels[it] = s;

        float4 bs = s_box[s];
        float a1 = (bs.z - bs.x) * (bs.w - bs.y);
        for (int i = tid; i < NBOX; i += 256) {
            float4 b = s_box[i];
            float ix1 = fmaxf(bs.x, b.x), iy1 = fmaxf(bs.y, b.y);
            float ix2 = fminf(bs.z, b.z), iy2 = fminf(bs.w, b.w);
            float inter = fmaxf(ix2 - ix1, 0.f) * fmaxf(iy2 - iy1, 0.f);
            float a2 = (b.z - b.x) * (b.w - b.y);
            float iou = inter / (a1 + a2 - inter);
            if (!(iou <= 0.6f)) s_fg[i] = -INFINITY;
        }
        __syncthreads();
    }

    if (tid < NKEEP) {
        int s = s_sels[tid];
        float4 b = s_box[s];
        int x = (int)floorf(b.x / 32.0f + 0.5f);
        int y = (int)floorf(b.y / 32.0f + 0.5f);
        int w = (int)floorf(b.z / 32.0f + 1.0f);
        int h = (int)floorf(b.w / 32.0f + 1.0f);
        bool bad = (x < 0) || (x >= FWW) || (y < 0) || (y >= FH) ||
                   (w < 1) || (x + w > FWW) || (h < 1) || (y + h > FH);
        if (bad) { x = 0; y = 0; w = FWW; h = FH; }
        roi_out[tid*4+0] = x; roi_out[tid*4+1] = y;
        roi_out[tid*4+2] = w; roi_out[tid*4+3] = h;
    }
}

// ---------------------------------------------------------------------------
// Kernel 2: adaptive 7x7 max-pool. pooled flat: idx = r*D1 + c*49 + i*7 + j
// ---------------------------------------------------------------------------
__global__ __launch_bounds__(256) void roi_pool_kernel(const float* __restrict__ feat,
                                                       const int* __restrict__ roi_out,
                                                       float* __restrict__ pooled) {
    int idx = blockIdx.x * 256 + threadIdx.x;
    if (idx >= NKEEP * D1) return;
    int r    = idx / D1;
    int rem  = idx - r * D1;
    int c    = rem / 49;
    int cell = rem - c * 49;
    int i = cell / 7;
    int j = cell - i * 7;
    int x = roi_out[r*4+0], y = roi_out[r*4+1], w = roi_out[r*4+2], h = roi_out[r*4+3];
    int r0 = y + (i * h) / 7;
    int r1 = y + ((i + 1) * h + 6) / 7;
    int c0 = x + (j * w) / 7;
    int c1 = x + ((j + 1) * w + 6) / 7;
    const float* fc = feat + (size_t)c * (FH * FWW);
    float m = -INFINITY;
    for (int rr = r0; rr < r1; ++rr) {
        const float* fr = fc + rr * FWW;
        for (int cc2 = c0; cc2 < c1; ++cc2) m = fmaxf(m, fr[cc2]);
    }
    pooled[idx] = m;
}

// ---------------------------------------------------------------------------
// Kernel 3: o[n][k] = b[k]  (bias init; fc1 R5-half atomically accumulates)
// ---------------------------------------------------------------------------
__global__ __launch_bounds__(256) void init_bias8_kernel(const float* __restrict__ b,
                                                         float* __restrict__ o, int K) {
    int i = blockIdx.x * 256 + threadIdx.x;
    if (i < NKEEP * K) o[i] = b[i & (K - 1)];
}

// ---------------------------------------------------------------------------
// Kernel 4a: FC1 control (exact R5 kernel), rows 0..2047 (kb 0..31).
// Per-row w requests: 256B chunks, 16 rows interleaved per wave.
// ---------------------------------------------------------------------------
__global__ __launch_bounds__(256) void fc1_kernel(const float* __restrict__ w1,
                                                  const float* __restrict__ flat,
                                                  float* __restrict__ o1) {
    const int kb = blockIdx.x >> 4;       // 0..31
    const int ds = blockIdx.x & 15;       // 0..15
    const int tid = threadIdx.x;
    const int kq = tid >> 4;              // 0..15
    const int dl = tid & 15;              // 0..15
    const int k0 = kb * 64 + kq * 4;
    const int dbase = ds * DPS + dl * 4;

    const float* wp = w1 + (size_t)k0 * D1 + dbase;
    const float* fp = flat + dbase;

    float acc[4][8];
    #pragma unroll
    for (int a = 0; a < 4; ++a)
        #pragma unroll
        for (int n = 0; n < 8; ++n) acc[a][n] = 0.f;

    v4 wa[4];
    #pragma unroll
    for (int a = 0; a < 4; ++a) wa[a] = *(const v4*)(wp + (size_t)a * D1);

    for (int itn = 0; itn < DPS / 64; ++itn) {   // 98 iters of 64 cols
        const int off  = itn * 64;
        const int offn = (itn < DPS / 64 - 1) ? off + 64 : off;

        v4 fv[8];
        #pragma unroll
        for (int n = 0; n < 8; ++n) fv[n] = *(const v4*)(fp + (size_t)n * D1 + off);

        v4 wb[4];
        #pragma unroll
        for (int a = 0; a < 4; ++a) wb[a] = *(const v4*)(wp + (size_t)a * D1 + offn);

        #pragma unroll
        for (int n = 0; n < 8; ++n) {
            acc[0][n] += wa[0][0]*fv[n][0] + wa[0][1]*fv[n][1] + wa[0][2]*fv[n][2] + wa[0][3]*fv[n][3];
            acc[1][n] += wa[1][0]*fv[n][0] + wa[1][1]*fv[n][1] + wa[1][2]*fv[n][2] + wa[1][3]*fv[n][3];
            acc[2][n] += wa[2][0]*fv[n][0] + wa[2][1]*fv[n][1] + wa[2][2]*fv[n][2] + wa[2][3]*fv[n][3];
            acc[3][n] += wa[3][0]*fv[n][0] + wa[3][1]*fv[n][1] + wa[3][2]*fv[n][2] + wa[3][3]*fv[n][3];
        }

        #pragma unroll
        for (int a = 0; a < 4; ++a) wa[a] = wb[a];
    }

    #pragma unroll
    for (int a = 0; a < 4; ++a) {
        #pragma unroll
        for (int n = 0; n < 8; ++n) {
            float v = acc[a][n];
            v += __shfl_xor(v, 1);
            v += __shfl_xor(v, 2);
            v += __shfl_xor(v, 4);
            v += __shfl_xor(v, 8);
            if (dl == 0) atomicAdd(&o1[n * K1 + k0 + a], v);
        }
    }
}

// ---------------------------------------------------------------------------
// Kernel 4b: FC1 experiment — rows 2048..4095. Wave owns 4 rows; each w
// instruction reads a contiguous 1KB of ONE row, and the x2-tile unroll
// groups 2KB back-to-back per row (DRAM row-buffer friendly). 16 rows/block
// keeps f L2 traffic ~820MB-scale. Direct o1 store (overwrites bias init).
// ---------------------------------------------------------------------------
__global__ __launch_bounds__(256) void fc1_waverow_kernel(const float* __restrict__ w1,
                                                          const float* __restrict__ flat,
                                                          const float* __restrict__ b1,
                                                          float* __restrict__ o1) {
    const int bid = blockIdx.x;           // 0..3583
    const int rg  = bid / 28;             // 0..127
    const int ds  = bid - rg * 28;        // 0..27
    const int wid  = threadIdx.x >> 6;    // 0..3
    const int lane = threadIdx.x & 63;
    const int row0  = 2048 + rg * 16 + wid * 4;
    const int dbase = ds * 3584;          // 28 * 3584 = D1

    const float* wp = w1 + (size_t)row0 * D1 + dbase + lane * 4;
    const float* fp = flat + dbase + lane * 4;

    float acc[4][8];
    #pragma unroll
    for (int a = 0; a < 4; ++a)
        #pragma unroll
        for (int n = 0; n < 8; ++n) acc[a][n] = 0.f;

    for (int t2 = 0; t2 < 7; ++t2) {      // 7 x (2 tiles x 256 floats) = 3584
        const int off0 = t2 * 512;
        const int off1 = off0 + 256;

        // w: 2KB back-to-back per row, row-major issue order
        v4 wA[4], wB[4];
        #pragma unroll
        for (int a = 0; a < 4; ++a) {
            wA[a] = *(const v4*)(wp + (size_t)a * D1 + off0);
            wB[a] = *(const v4*)(wp + (size_t)a * D1 + off1);
        }

        {   // tile 0
            v4 fv[8];
            #pragma unroll
            for (int n = 0; n < 8; ++n) fv[n] = *(const v4*)(fp + (size_t)n * D1 + off0);
            #pragma unroll
            for (int n = 0; n < 8; ++n) {
                acc[0][n] += wA[0][0]*fv[n][0] + wA[0][1]*fv[n][1] + wA[0][2]*fv[n][2] + wA[0][3]*fv[n][3];
                acc[1][n] += wA[1][0]*fv[n][0] + wA[1][1]*fv[n][1] + wA[1][2]*fv[n][2] + wA[1][3]*fv[n][3];
                acc[2][n] += wA[2][0]*fv[n][0] + wA[2][1]*fv[n][1] + wA[2][2]*fv[n][2] + wA[2][3]*fv[n][3];
                acc[3][n] += wA[3][0]*fv[n][0] + wA[3][1]*fv[n][1] + wA[3][2]*fv[n][2] + wA[3][3]*fv[n][3];
            }
        }
        {   // tile 1
            v4 fv[8];
            #pragma unroll
            for (int n = 0; n < 8; ++n) fv[n] = *(const v4*)(fp + (size_t)n * D1 + off1);
            #pragma unroll
            for (int n = 0; n < 8; ++n) {
                acc[0][n] += wB[0][0]*fv[n][0] + wB[0][1]*fv[n][1] + wB[0][2]*fv[n][2] + wB[0][3]*fv[n][3];
                acc[1][n] += wB[1][0]*fv[n][0] + wB[1][1]*fv[n][1] + wB[1][2]*fv[n][2] + wB[1][3]*fv[n][3];
                acc[2][n] += wB[2][0]*fv[n][0] + wB[2][1]*fv[n][1] + wB[2][2]*fv[n][2] + wB[2][3]*fv[n][3];
                acc[3][n] += wB[3][0]*fv[n][0] + wB[3][1]*fv[n][1] + wB[3][2]*fv[n][2] + wB[3][3]*fv[n][3];
            }
        }
    }

    // full-wave reduce per (row, roi); partial across 28 d-slices via atomic
    #pragma unroll
    for (int a = 0; a < 4; ++a) {
        #pragma unroll
        for (int n = 0; n < 8; ++n) {
            float v = acc[a][n];
            v += __shfl_xor(v, 1);
            v += __shfl_xor(v, 2);
            v += __shfl_xor(v, 4);
            v += __shfl_xor(v, 8);
            v += __shfl_xor(v, 16);
            v += __shfl_xor(v, 32);
            if (lane == 0) atomicAdd(&o1[n * K1 + row0 + a], v);
        }
    }
}

// ---------------------------------------------------------------------------
// Kernel 5: FC2 (8x4096)@(4096x4096). One wave per output row k.
// ---------------------------------------------------------------------------
__global__ __launch_bounds__(256) void fc2_kernel(const float* __restrict__ w2,
                                                  const float* __restrict__ o1,
                                                  const float* __restrict__ b2,
                                                  float* __restrict__ o2) {
    int gw   = (blockIdx.x * 256 + threadIdx.x) >> 6;
    int lane = threadIdx.x & 63;
    if (gw >= K1) return;
    const float4* wr = (const float4*)(w2 + (size_t)gw * K1);
    const float4* fo = (const float4*)o1;
    float acc[8];
    #pragma unroll
    for (int n = 0; n < 8; ++n) acc[n] = 0.f;
    for (int itn = 0; itn < K1 / 256; ++itn) {   // 16
        float4 wv = wr[itn * 64 + lane];
        #pragma unroll
        for (int n = 0; n < 8; ++n) {
            float4 f = fo[n * (K1/4) + itn * 64 + lane];
            acc[n] += wv.x*f.x + wv.y*f.y + wv.z*f.z + wv.w*f.w;
        }
    }
    #pragma unroll
    for (int n = 0; n < 8; ++n) {
        float v = acc[n];
        #pragma unroll
        for (int m = 32; m >= 1; m >>= 1) v += __shfl_xor(v, m);
        if (lane == 0) o2[n * K1 + gw] = v + b2[gw];
    }
}

// ---------------------------------------------------------------------------
// Kernel 6: heads. k<81 -> wc/bc, else wl/bl. out (8,405) row-major.
// ---------------------------------------------------------------------------
__global__ __launch_bounds__(256) void fc3_kernel(const float* __restrict__ wc,
                                                  const float* __restrict__ bc,
                                                  const float* __restrict__ wl,
                                                  const float* __restrict__ bl,
                                                  const float* __restrict__ o2,
                                                  float* __restrict__ out) {
    int gw   = (blockIdx.x * 256 + threadIdx.x) >> 6;
    int lane = threadIdx.x & 63;
    if (gw >= 405) return;
    const float* wrow; float bias;
    if (gw < 81) { wrow = wc + (size_t)gw * K1;        bias = bc[gw]; }
    else         { wrow = wl + (size_t)(gw - 81) * K1; bias = bl[gw - 81]; }
    const float4* wr = (const float4*)wrow;
    const float4* fo = (const float4*)o2;
    float acc[8];
    #pragma unroll
    for (int n = 0; n < 8; ++n) acc[n] = 0.f;
    for (int itn = 0; itn < K1 / 256; ++itn) {
        float4 wv = wr[itn * 64 + lane];
        #pragma unroll
        for (int n = 0; n < 8; ++n) {
            float4 f = fo[n * (K1/4) + itn * 64 + lane];
            acc[n] += wv.x*f.x + wv.y*f.y + wv.z*f.z + wv.w*f.w;
        }
    }
    #pragma unroll
    for (int n = 0; n < 8; ++n) {
        float v = acc[n];
        #pragma unroll
        for (int m = 32; m >= 1; m >>= 1) v += __shfl_xor(v, m);
        if (lane == 0) out[n * 405 + gw] = v + bias;
    }
}

// ---------------------------------------------------------------------------
extern "C" void kernel_launch(void* const* d_in, const int* in_sizes, int n_in,
                              void* d_out, int out_size, void* d_ws, size_t ws_size,
                              hipStream_t stream) {
    const float* feat   = (const float*)d_in[0];
    const float* rois   = (const float*)d_in[1];
    const float* scores = (const float*)d_in[2];
    const float* w1     = (const float*)d_in[3];
    const float* b1     = (const float*)d_in[4];
    const float* w2     = (const float*)d_in[5];
    const float* b2     = (const float*)d_in[6];
    const float* wc     = (const float*)d_in[7];
    const float* bc     = (const float*)d_in[8];
    const float* wl     = (const float*)d_in[9];
    const float* bl     = (const float*)d_in[10];
    float* out = (float*)d_out;

    // workspace layout (floats): [0..255] roi ints, then pooled, o1, o2
    int*   roi_out = (int*)d_ws;
    float* pooled  = (float*)d_ws + 256;
    float* o1      = pooled + (size_t)NKEEP * D1;
    float* o2      = o1 + NKEEP * K1;

    nms_sel_kernel<<<1, 256, 0, stream>>>(rois, scores, roi_out);
    roi_pool_kernel<<<(NKEEP * D1 + 255) / 256, 256, 0, stream>>>(feat, roi_out, pooled);
    init_bias8_kernel<<<(NKEEP * K1 + 255) / 256, 256, 0, stream>>>(b1, o1, K1);
    fc1_kernel<<<32 * NSLICE, 256, 0, stream>>>(w1, pooled, o1);            // rows 0..2047
    fc1_waverow_kernel<<<128 * 28, 256, 0, stream>>>(w1, pooled, b1, o1);   // rows 2048..4095
    fc2_kernel<<<K1 / 4, 256, 0, stream>>>(w2, o1, b2, o2);
    fc3_kernel<<<(405 * 64 + 255) / 256, 256, 0, stream>>>(wc, bc, wl, bl, o2, out);
}

// Round 9
// 383.981 us; speedup vs baseline: 2.2383x; 1.5453x over previous
//
#include <hip/hip_runtime.h>
#include <cstddef>
#include <math.h>

typedef float v4 __attribute__((ext_vector_type(4)));

#define IMG_H 800
#define IMG_W 1216
#define FH 25
#define FWW 38
#define NBOX 2000
#define NKEEP 8
#define D1 100352   /* 2048*49 */
#define K1 4096
#define NSLICE 16
#define DPS (D1/NSLICE)  /* 6272 */

__device__ inline v4 ldnt4(const float* p) {
    return __builtin_nontemporal_load((const v4*)p);
}

// ---------------------------------------------------------------------------
// Kernel 1: greedy NMS (exact replica of reference loop) + ROI quantization.
// ---------------------------------------------------------------------------
__global__ __launch_bounds__(256) void nms_sel_kernel(const float* __restrict__ rois,
                                                      const float* __restrict__ scores,
                                                      int* __restrict__ roi_out) {
    __shared__ float4 s_box[NBOX];
    __shared__ float  s_fg[NBOX];
    __shared__ float  red_v[256];
    __shared__ int    red_i[256];
    __shared__ int    s_sels[NKEEP];
    const int tid = threadIdx.x;

    for (int i = tid; i < NBOX; i += 256) {
        float x1 = rois[i*4+0], y1 = rois[i*4+1], x2 = rois[i*4+2], y2 = rois[i*4+3];
        s_box[i] = make_float4(x1, y1, x2, y2);
        bool valid = (x1 >= 0.f) && (y1 >= 0.f) && (x2 <= (float)IMG_W) && (y2 <= (float)IMG_H);
        s_fg[i] = valid ? scores[i*2+1] : -INFINITY;
    }
    __syncthreads();

    for (int it = 0; it < NKEEP; ++it) {
        float bv = -INFINITY; int bi = NBOX;
        for (int i = tid; i < NBOX; i += 256) {
            float v = s_fg[i];
            if (v > bv || (v == bv && i < bi)) { bv = v; bi = i; }
        }
        red_v[tid] = bv; red_i[tid] = bi;
        __syncthreads();
        for (int off = 128; off > 0; off >>= 1) {
            if (tid < off) {
                float v = red_v[tid+off]; int ii = red_i[tid+off];
                if (v > red_v[tid] || (v == red_v[tid] && ii < red_i[tid])) {
                    red_v[tid] = v; red_i[tid] = ii;
                }
            }
            __syncthreads();
        }
        int s = red_i[0];
        if (s >= NBOX) s = 0;
        if (tid == 0) s_sels[it] = s;

        float4 bs = s_box[s];
        float a1 = (bs.z - bs.x) * (bs.w - bs.y);
        for (int i = tid; i < NBOX; i += 256) {
            float4 b = s_box[i];
            float ix1 = fmaxf(bs.x, b.x), iy1 = fmaxf(bs.y, b.y);
            float ix2 = fminf(bs.z, b.z), iy2 = fminf(bs.w, b.w);
            float inter = fmaxf(ix2 - ix1, 0.f) * fmaxf(iy2 - iy1, 0.f);
            float a2 = (b.z - b.x) * (b.w - b.y);
            float iou = inter / (a1 + a2 - inter);
            if (!(iou <= 0.6f)) s_fg[i] = -INFINITY;
        }
        __syncthreads();
    }

    if (tid < NKEEP) {
        int s = s_sels[tid];
        float4 b = s_box[s];
        int x = (int)floorf(b.x / 32.0f + 0.5f);
        int y = (int)floorf(b.y / 32.0f + 0.5f);
        int w = (int)floorf(b.z / 32.0f + 1.0f);
        int h = (int)floorf(b.w / 32.0f + 1.0f);
        bool bad = (x < 0) || (x >= FWW) || (y < 0) || (y >= FH) ||
                   (w < 1) || (x + w > FWW) || (h < 1) || (y + h > FH);
        if (bad) { x = 0; y = 0; w = FWW; h = FH; }
        roi_out[tid*4+0] = x; roi_out[tid*4+1] = y;
        roi_out[tid*4+2] = w; roi_out[tid*4+3] = h;
    }
}

// ---------------------------------------------------------------------------
// Kernel 2: adaptive 7x7 max-pool. pooled flat: idx = r*D1 + c*49 + i*7 + j
// ---------------------------------------------------------------------------
__global__ __launch_bounds__(256) void roi_pool_kernel(const float* __restrict__ feat,
                                                       const int* __restrict__ roi_out,
                                                       float* __restrict__ pooled) {
    int idx = blockIdx.x * 256 + threadIdx.x;
    if (idx >= NKEEP * D1) return;
    int r    = idx / D1;
    int rem  = idx - r * D1;
    int c    = rem / 49;
    int cell = rem - c * 49;
    int i = cell / 7;
    int j = cell - i * 7;
    int x = roi_out[r*4+0], y = roi_out[r*4+1], w = roi_out[r*4+2], h = roi_out[r*4+3];
    int r0 = y + (i * h) / 7;
    int r1 = y + ((i + 1) * h + 6) / 7;
    int c0 = x + (j * w) / 7;
    int c1 = x + ((j + 1) * w + 6) / 7;
    const float* fc = feat + (size_t)c * (FH * FWW);
    float m = -INFINITY;
    for (int rr = r0; rr < r1; ++rr) {
        const float* fr = fc + rr * FWW;
        for (int cc2 = c0; cc2 < c1; ++cc2) m = fmaxf(m, fr[cc2]);
    }
    pooled[idx] = m;
}

// ---------------------------------------------------------------------------
// Kernel 3: o[n][k] = b[k]  (bias init; fc1 atomically accumulates on top)
// ---------------------------------------------------------------------------
__global__ __launch_bounds__(256) void init_bias8_kernel(const float* __restrict__ b,
                                                         float* __restrict__ o, int K) {
    int i = blockIdx.x * 256 + threadIdx.x;
    if (i < NKEEP * K) o[i] = b[i & (K - 1)];
}

// ---------------------------------------------------------------------------
// Kernel 4: FC1 — exact R5 structure (best known: 405us total). ONE change:
// w-loads are nontemporal so the 1.64GB stream doesn't evict the 3.2MB
// activation working set from L2 (f re-reads total 3.3GB; if they thrash
// to HBM they inflate FETCH and stall the loop).
// ---------------------------------------------------------------------------
__global__ __launch_bounds__(256) void fc1_kernel(const float* __restrict__ w1,
                                                  const float* __restrict__ flat,
                                                  float* __restrict__ o1) {
    const int kb = blockIdx.x >> 4;       // 0..63
    const int ds = blockIdx.x & 15;       // 0..15
    const int tid = threadIdx.x;
    const int kq = tid >> 4;              // 0..15
    const int dl = tid & 15;              // 0..15
    const int k0 = kb * 64 + kq * 4;
    const int dbase = ds * DPS + dl * 4;

    const float* wp = w1 + (size_t)k0 * D1 + dbase;
    const float* fp = flat + dbase;

    float acc[4][8];
    #pragma unroll
    for (int a = 0; a < 4; ++a)
        #pragma unroll
        for (int n = 0; n < 8; ++n) acc[a][n] = 0.f;

    // preload iter-0 w (nontemporal)
    v4 wa[4];
    #pragma unroll
    for (int a = 0; a < 4; ++a) wa[a] = ldnt4(wp + (size_t)a * D1);

    for (int itn = 0; itn < DPS / 64; ++itn) {   // 98 iters of 64 cols
        const int off  = itn * 64;
        const int offn = (itn < DPS / 64 - 1) ? off + 64 : off;  // dummy last

        // (1) f loads — want these L2-resident (protected by nt on w)
        v4 fv[8];
        #pragma unroll
        for (int n = 0; n < 8; ++n) fv[n] = *(const v4*)(fp + (size_t)n * D1 + off);

        // (2) prefetch next iteration's w — nontemporal, stays in flight
        v4 wb[4];
        #pragma unroll
        for (int a = 0; a < 4; ++a) wb[a] = ldnt4(wp + (size_t)a * D1 + offn);

        // (3) FMA block on the w loaded one iteration ago
        #pragma unroll
        for (int n = 0; n < 8; ++n) {
            acc[0][n] += wa[0][0]*fv[n][0] + wa[0][1]*fv[n][1] + wa[0][2]*fv[n][2] + wa[0][3]*fv[n][3];
            acc[1][n] += wa[1][0]*fv[n][0] + wa[1][1]*fv[n][1] + wa[1][2]*fv[n][2] + wa[1][3]*fv[n][3];
            acc[2][n] += wa[2][0]*fv[n][0] + wa[2][1]*fv[n][1] + wa[2][2]*fv[n][2] + wa[2][3]*fv[n][3];
            acc[3][n] += wa[3][0]*fv[n][0] + wa[3][1]*fv[n][1] + wa[3][2]*fv[n][2] + wa[3][3]*fv[n][3];
        }

        #pragma unroll
        for (int a = 0; a < 4; ++a) wa[a] = wb[a];
    }

    // reduce across the 16 d-lanes, then atomic into o1
    #pragma unroll
    for (int a = 0; a < 4; ++a) {
        #pragma unroll
        for (int n = 0; n < 8; ++n) {
            float v = acc[a][n];
            v += __shfl_xor(v, 1);
            v += __shfl_xor(v, 2);
            v += __shfl_xor(v, 4);
            v += __shfl_xor(v, 8);
            if (dl == 0) atomicAdd(&o1[n * K1 + k0 + a], v);
        }
    }
}

// ---------------------------------------------------------------------------
// Kernel 5: FC2 (8x4096)@(4096x4096). One wave per output row; nt w-loads.
// ---------------------------------------------------------------------------
__global__ __launch_bounds__(256) void fc2_kernel(const float* __restrict__ w2,
                                                  const float* __restrict__ o1,
                                                  const float* __restrict__ b2,
                                                  float* __restrict__ o2) {
    int gw   = (blockIdx.x * 256 + threadIdx.x) >> 6;
    int lane = threadIdx.x & 63;
    if (gw >= K1) return;
    const float* wr = w2 + (size_t)gw * K1;
    const v4* fo = (const v4*)o1;
    float acc[8];
    #pragma unroll
    for (int n = 0; n < 8; ++n) acc[n] = 0.f;
    for (int itn = 0; itn < K1 / 256; ++itn) {   // 16
        v4 wv = ldnt4(wr + (itn * 64 + lane) * 4);
        #pragma unroll
        for (int n = 0; n < 8; ++n) {
            v4 f = fo[n * (K1/4) + itn * 64 + lane];
            acc[n] += wv[0]*f[0] + wv[1]*f[1] + wv[2]*f[2] + wv[3]*f[3];
        }
    }
    #pragma unroll
    for (int n = 0; n < 8; ++n) {
        float v = acc[n];
        #pragma unroll
        for (int m = 32; m >= 1; m >>= 1) v += __shfl_xor(v, m);
        if (lane == 0) o2[n * K1 + gw] = v + b2[gw];
    }
}

// ---------------------------------------------------------------------------
// Kernel 6: heads. k<81 -> wc/bc, else wl/bl. out (8,405) row-major.
// ---------------------------------------------------------------------------
__global__ __launch_bounds__(256) void fc3_kernel(const float* __restrict__ wc,
                                                  const float* __restrict__ bc,
                                                  const float* __restrict__ wl,
                                                  const float* __restrict__ bl,
                                                  const float* __restrict__ o2,
                                                  float* __restrict__ out) {
    int gw   = (blockIdx.x * 256 + threadIdx.x) >> 6;
    int lane = threadIdx.x & 63;
    if (gw >= 405) return;
    const float* wrow; float bias;
    if (gw < 81) { wrow = wc + (size_t)gw * K1;        bias = bc[gw]; }
    else         { wrow = wl + (size_t)(gw - 81) * K1; bias = bl[gw - 81]; }
    const v4* fo = (const v4*)o2;
    float acc[8];
    #pragma unroll
    for (int n = 0; n < 8; ++n) acc[n] = 0.f;
    for (int itn = 0; itn < K1 / 256; ++itn) {
        v4 wv = ldnt4(wrow + (itn * 64 + lane) * 4);
        #pragma unroll
        for (int n = 0; n < 8; ++n) {
            v4 f = fo[n * (K1/4) + itn * 64 + lane];
            acc[n] += wv[0]*f[0] + wv[1]*f[1] + wv[2]*f[2] + wv[3]*f[3];
        }
    }
    #pragma unroll
    for (int n = 0; n < 8; ++n) {
        float v = acc[n];
        #pragma unroll
        for (int m = 32; m >= 1; m >>= 1) v += __shfl_xor(v, m);
        if (lane == 0) out[n * 405 + gw] = v + bias;
    }
}

// ---------------------------------------------------------------------------
extern "C" void kernel_launch(void* const* d_in, const int* in_sizes, int n_in,
                              void* d_out, int out_size, void* d_ws, size_t ws_size,
                              hipStream_t stream) {
    const float* feat   = (const float*)d_in[0];
    const float* rois   = (const float*)d_in[1];
    const float* scores = (const float*)d_in[2];
    const float* w1     = (const float*)d_in[3];
    const float* b1     = (const float*)d_in[4];
    const float* w2     = (const float*)d_in[5];
    const float* b2     = (const float*)d_in[6];
    const float* wc     = (const float*)d_in[7];
    const float* bc     = (const float*)d_in[8];
    const float* wl     = (const float*)d_in[9];
    const float* bl     = (const float*)d_in[10];
    float* out = (float*)d_out;

    // workspace layout (floats): [0..255] roi ints, then pooled, o1, o2
    int*   roi_out = (int*)d_ws;
    float* pooled  = (float*)d_ws + 256;
    float* o1      = pooled + (size_t)NKEEP * D1;
    float* o2      = o1 + NKEEP * K1;

    nms_sel_kernel<<<1, 256, 0, stream>>>(rois, scores, roi_out);
    roi_pool_kernel<<<(NKEEP * D1 + 255) / 256, 256, 0, stream>>>(feat, roi_out, pooled);
    init_bias8_kernel<<<(NKEEP * K1 + 255) / 256, 256, 0, stream>>>(b1, o1, K1);
    fc1_kernel<<<64 * NSLICE, 256, 0, stream>>>(w1, pooled, o1);
    fc2_kernel<<<K1 / 4, 256, 0, stream>>>(w2, o1, b2, o2);
    fc3_kernel<<<(405 * 64 + 255) / 256, 256, 0, stream>>>(wc, bc, wl, bl, o2, out);
}